// Round 6
// baseline (560.873 us; speedup 1.0000x reference)
//
#include <hip/hip_runtime.h>
#include <math.h>

#define NROWS  16384   // B*S
#define DMODEL 1024
#define NHEAD  16
#define HDIM   64
#define SEQ    4096
#define NBATCH 4
#define NBH    64      // NBATCH*NHEAD
#define SCHUNK 16      // split-K chunks over S for kv aggregation
#define W1     2097152u   // one split weight matrix [1024][2048] in ushorts

typedef __attribute__((ext_vector_type(8))) short bf16x8;
typedef __attribute__((ext_vector_type(4))) float f32x4;

#define VMCNT(N) asm volatile("s_waitcnt vmcnt(" #N ")" ::: "memory")
#define BAR() do { asm volatile("" ::: "memory"); __builtin_amdgcn_s_barrier(); \
                   asm volatile("" ::: "memory"); } while (0)

__device__ __forceinline__ unsigned short f2bf(float f) {
    unsigned u = __float_as_uint(f);
    u += 0x7FFFu + ((u >> 16) & 1u);   // round-to-nearest-even
    return (unsigned short)(u >> 16);
}
__device__ __forceinline__ float bf2f(unsigned short h) {
    return __uint_as_float((unsigned)h << 16);
}

__device__ __forceinline__ void gload16(const void* g, void* l) {
    __builtin_amdgcn_global_load_lds(
        (const __attribute__((address_space(1))) unsigned int*)g,
        (__attribute__((address_space(3))) unsigned int*)l, 16, 0, 0);
}

// ---------------------------------------------------------------------------
// split x [M][1024] f32 -> xs [M][2048] bf16 (cols 0-1023 = hi, 1024-2047 = lo)
// ---------------------------------------------------------------------------
__global__ __launch_bounds__(256)
void split_x(const float* __restrict__ a, unsigned short* __restrict__ dst)
{
    const int idx = blockIdx.x * 256 + threadIdx.x;   // over M*1024/4
    const int row = idx >> 8;
    const int c4  = (idx & 255) * 4;
    const float4 v = ((const float4*)a)[idx];
    ushort4 H, L;
    H.x = f2bf(v.x); L.x = f2bf(v.x - bf2f(H.x));
    H.y = f2bf(v.y); L.y = f2bf(v.y - bf2f(H.y));
    H.z = f2bf(v.z); L.z = f2bf(v.z - bf2f(H.z));
    H.w = f2bf(v.w); L.w = f2bf(v.w - bf2f(H.w));
    *(ushort4*)&dst[(size_t)row * 2048 + c4]        = H;
    *(ushort4*)&dst[(size_t)row * 2048 + 1024 + c4] = L;
}

// all 4 weight matrices -> [y][1024][2048] bf16 hi|lo (y: 0=Wq 1=Wk 2=Wv 3=Wo)
__global__ __launch_bounds__(256)
void split_w4(const float* __restrict__ a0, const float* __restrict__ a1,
              const float* __restrict__ a2, const float* __restrict__ a3,
              unsigned short* __restrict__ dst)
{
    const int y = blockIdx.y;
    const float* src = (y == 0) ? a0 : (y == 1) ? a1 : (y == 2) ? a2 : a3;
    unsigned short* d = dst + (size_t)y * W1;
    const int idx = blockIdx.x * 256 + threadIdx.x;   // over 1024*1024/4
    const int row = idx >> 8;
    const int c4  = (idx & 255) * 4;
    const float4 v = ((const float4*)src)[idx];
    ushort4 H, L;
    H.x = f2bf(v.x); L.x = f2bf(v.x - bf2f(H.x));
    H.y = f2bf(v.y); L.y = f2bf(v.y - bf2f(H.y));
    H.z = f2bf(v.z); L.z = f2bf(v.z - bf2f(H.z));
    H.w = f2bf(v.w); L.w = f2bf(v.w - bf2f(H.w));
    *(ushort4*)&d[(size_t)row * 2048 + c4]        = H;
    *(ushort4*)&d[(size_t)row * 2048 + 1024 + c4] = L;
}

// ---------------------------------------------------------------------------
// Split GEMM as ONE bf16 GEMM, concatenated K=3072: terms [hh | hl | lh].
//   A-col = k<1024 ? k : k-1024   over xs [M][2048] = [xh|xl]
//   B-col = k<2048 ? k : k-2048   over Ws [N][2048] = [Wh|Wl]
// 256x256 tile, BK=32, 8 waves (2Mx4N), per-wave 128x64. Deep pipeline:
// 4 LDS buffers (4 x 32KB = 128 KiB), prefetch 3 tiles ahead, counted
// s_waitcnt vmcnt(8) -- loads NEVER drain to 0 in the main loop (T3+T4).
// ONE raw s_barrier per K-tile. Order: vmcnt -> barrier -> issue stage(kt+3)
// -> ds_read(kt) -> MFMA. (Issue-after-barrier makes the write target safe:
// its readers were sealed by this barrier.) LDS chunks stored TRANSPOSED
// ([slot][row] cells, via per-lane source permutation; LDS dest stays linear
// per gload_lds rules) so frag reads are 256B-contiguous = 2 lanes/bank = free.
// T5 setprio around the 32-MFMA cluster. T1 bijective XCD swizzle.
// ---------------------------------------------------------------------------
template<int ELU>
__global__ __launch_bounds__(512)
void gemm_p3(const unsigned short* __restrict__ A2, const unsigned short* __restrict__ W2,
             const float* __restrict__ bias, float* __restrict__ C)
{
    __shared__ unsigned short lds[65536];   // 4 buffers x 16384 ushorts (A 16KB + B 16KB)
    const int t    = threadIdx.x;
    const int lane = t & 63;
    const int wv   = t >> 6;        // wave 0..7
    const int wr   = wv >> 2;       // M half    0..1  (128 rows)
    const int wcn  = wv & 3;        // N quarter 0..3  (64 cols)

    // XCD swizzle (bijective, 256 blocks): 8 m-panels x 4 n per XCD
    const int bid  = blockIdx.x;
    const int swz  = ((bid & 7) << 5) | (bid >> 3);
    const int am0  = (swz >> 2) * 256;     // A panel row base
    const int bn0  = (swz & 3) * 256;      // W panel row base (= C col base)

    const int fr   = lane & 15;                    // frag row
    const int j0   = lane >> 4;                    // frag k-slot 0..3
    const unsigned fro = (unsigned)(j0 * 128 + fr * 8);  // frag read offset (ushorts)
    const int srcr = lane & 15;                    // staging source row-in-chunk
    const int srcc = (lane >> 4) * 8;              // staging source k-offset (ushorts)

    f32x4 acc[8][4];
#pragma unroll
    for (int i = 0; i < 8; ++i)
#pragma unroll
        for (int j = 0; j < 4; ++j)
#pragma unroll
            for (int e = 0; e < 4; ++e) acc[i][j][e] = 0.f;

    // stage K-tile kt into buffer kt&3: per wave 2 A-chunks + 2 B-chunks
    // (chunk = 16 rows x 32 k, stored as cell[slot][row]; dest linear in lane)
    auto stage_tile = [&](int kt) {
        const int k0  = kt * 32;
        const int kbA = (k0 < 1024) ? k0 : k0 - 1024;
        const int kbB = (k0 < 2048) ? k0 : k0 - 2048;
        const unsigned wb = ((unsigned)kt & 3u) * 16384u;
#pragma unroll
        for (int c = 0; c < 2; ++c) {
            const int ch = wv * 2 + c;
            gload16(A2 + (size_t)(am0 + ch * 16 + srcr) * 2048 + kbA + srcc,
                    (unsigned short*)&lds[wb + (unsigned)ch * 512u]);
            gload16(W2 + (size_t)(bn0 + ch * 16 + srcr) * 2048 + kbB + srcc,
                    (unsigned short*)&lds[wb + 8192u + (unsigned)ch * 512u]);
        }
    };

    // compute K-tile kt from buffer kt&3: 12 ds_read_b128 + 32 MFMA
    auto compute = [&](int kt) {
        const unsigned rd = ((unsigned)kt & 3u) * 16384u;
        bf16x8 a[8], b[4];
#pragma unroll
        for (int j = 0; j < 4; ++j)
            b[j] = *(const bf16x8*)&lds[rd + 8192u + (unsigned)((wcn * 4 + j) * 512) + fro];
#pragma unroll
        for (int i = 0; i < 8; ++i)
            a[i] = *(const bf16x8*)&lds[rd + (unsigned)((wr * 8 + i) * 512) + fro];
        __builtin_amdgcn_s_setprio(1);
#pragma unroll
        for (int i = 0; i < 8; ++i)
#pragma unroll
            for (int j = 0; j < 4; ++j)
                acc[i][j] = __builtin_amdgcn_mfma_f32_16x16x32_bf16(a[i], b[j], acc[i][j], 0, 0, 0);
        __builtin_amdgcn_s_setprio(0);
    };

    // prologue: 3 tiles in flight
    stage_tile(0); stage_tile(1); stage_tile(2);

    // steady state: 12 loads outstanding; vmcnt(8) retires the oldest tile's 4
    for (int kt = 0; kt < 93; ++kt) {
        VMCNT(8);
        BAR();
        stage_tile(kt + 3);
        compute(kt);
    }
    VMCNT(8); BAR(); compute(93);
    VMCNT(4); BAR(); compute(94);
    VMCNT(0); BAR(); compute(95);

    // epilogue: C/D layout col=lane&15, row=(lane>>4)*4+reg
    const int crow0 = am0 + wr * 128 + (lane >> 4) * 4;
    const int ccol0 = bn0 + wcn * 64 + fr;
#pragma unroll
    for (int j = 0; j < 4; ++j) {
        const int col = ccol0 + j * 16;
        const float bv = bias[col];
#pragma unroll
        for (int i = 0; i < 8; ++i) {
            const int row = crow0 + i * 16;
#pragma unroll
            for (int r = 0; r < 4; ++r) {
                float v = acc[i][j][r] + bv;
                if (ELU) v = (v > 0.f) ? (v + 1.f) : __expf(v);  // elu(v)+1
                C[(size_t)(row + r) * DMODEL + col] = v;
            }
        }
    }
}

// ---------------------------------------------------------------------------
// kv partials: for (b,h,sc): kvp[d][e] = sum_{s in chunk} k[s,d]*v[s,e],
// ksp[d] = sum k[s,d]. Deterministic split-K, no atomics.
// ---------------------------------------------------------------------------
__global__ __launch_bounds__(512)
void kv_partial(const float* __restrict__ k, const float* __restrict__ v,
                float* __restrict__ kvp, float* __restrict__ ksp)
{
    __shared__ float Ks[32][64];
    __shared__ float Vs[32][64];
    const int t  = threadIdx.x;
    const int bh = blockIdx.x;
    const int b  = bh >> 4;
    const int h  = bh & 15;
    const int sc = blockIdx.y;
    const int d  = t & 63;
    const int e0 = (t >> 6) * 8;

    float acc[8];
#pragma unroll
    for (int j = 0; j < 8; ++j) acc[j] = 0.f;
    float ks = 0.f;

    const size_t rowbase = (size_t)b * SEQ;
    const int sbeg = sc * (SEQ / SCHUNK);       // 256 rows per chunk
    const int send = sbeg + (SEQ / SCHUNK);
    const int lrow = t >> 4;                    // staging: 0..31
    const int lc4  = (t & 15) * 4;

    for (int s0 = sbeg; s0 < send; s0 += 32) {
        const size_t g = (rowbase + s0 + lrow) * DMODEL + h * HDIM + lc4;
        *(float4*)&Ks[lrow][lc4] = *(const float4*)&k[g];
        *(float4*)&Vs[lrow][lc4] = *(const float4*)&v[g];
        __syncthreads();
#pragma unroll 8
        for (int sp = 0; sp < 32; ++sp) {
            const float kd = Ks[sp][d];
            if (t < 64) ks += Ks[sp][t];        // wave 0 only (wave-uniform branch)
            const float4 v0 = *(const float4*)&Vs[sp][e0 + 0];
            const float4 v1 = *(const float4*)&Vs[sp][e0 + 4];
            acc[0] = fmaf(kd, v0.x, acc[0]);  acc[1] = fmaf(kd, v0.y, acc[1]);
            acc[2] = fmaf(kd, v0.z, acc[2]);  acc[3] = fmaf(kd, v0.w, acc[3]);
            acc[4] = fmaf(kd, v1.x, acc[4]);  acc[5] = fmaf(kd, v1.y, acc[5]);
            acc[6] = fmaf(kd, v1.z, acc[6]);  acc[7] = fmaf(kd, v1.w, acc[7]);
        }
        __syncthreads();
    }

    const size_t base = ((size_t)sc * NBH + bh) * HDIM;
    float4 o0; o0.x = acc[0]; o0.y = acc[1]; o0.z = acc[2]; o0.w = acc[3];
    float4 o1; o1.x = acc[4]; o1.y = acc[5]; o1.z = acc[6]; o1.w = acc[7];
    *(float4*)&kvp[(base + d) * HDIM + e0 + 0] = o0;
    *(float4*)&kvp[(base + d) * HDIM + e0 + 4] = o1;
    if (t < 64) ksp[base + t] = ks;
}

__global__ __launch_bounds__(256)
void kv_reduce(const float* __restrict__ kvp, const float* __restrict__ ksp,
               float* __restrict__ kv, float* __restrict__ ksum)
{
    const int i = blockIdx.x * 256 + threadIdx.x;
    const int NKV = NBH * HDIM * HDIM;
    if (i < NKV) {
        float s = 0.f;
#pragma unroll
        for (int c = 0; c < SCHUNK; ++c) s += kvp[(size_t)c * NKV + i];
        kv[i] = s;
    }
    if (i < NBH * HDIM) {
        float s = 0.f;
#pragma unroll
        for (int c = 0; c < SCHUNK; ++c) s += ksp[(size_t)c * NBH * HDIM + i];
        ksum[i] = s;
    }
}

// ---------------------------------------------------------------------------
// att[s,e] = (sum_d q[s,d]*kv[d,e]) / (sum_d q[s,d]*ksum[d] + 1e-6),
// written directly as bf16 hi/lo into the [M][2048] concat layout.
// ---------------------------------------------------------------------------
__global__ __launch_bounds__(256)
void qkv_norm(const float* __restrict__ q, const float* __restrict__ kv,
              const float* __restrict__ ksum, unsigned short* __restrict__ att)
{
    __shared__ float Qs[64][68];
    __shared__ float KVs[64][64];
    __shared__ float kss[64];
    const int t  = threadIdx.x;
    const int s0 = blockIdx.x * 64;
    const int b  = blockIdx.y;
    const int h  = blockIdx.z;
    const int bh = b * NHEAD + h;

#pragma unroll
    for (int i = 0; i < 4; ++i) {
        const int idx = i * 256 + t;
        const int row = idx >> 4;
        const int c4  = (idx & 15) * 4;
        const float4 vq = *(const float4*)&q[((size_t)b * SEQ + s0 + row) * DMODEL + h * HDIM + c4];
        *(float4*)&Qs[row][c4] = vq;
        *(float4*)&((float*)KVs)[idx * 4] = *(const float4*)&kv[(size_t)bh * HDIM * HDIM + idx * 4];
    }
    if (t < 64) kss[t] = ksum[(size_t)bh * HDIM + t];
    __syncthreads();

    const int r  = t >> 2;
    const int e0 = (t & 3) * 16;
    float out[16];
#pragma unroll
    for (int j = 0; j < 16; ++j) out[j] = 0.f;
    float nrm = 0.f;

#pragma unroll 8
    for (int d = 0; d < 64; ++d) {
        const float qd = Qs[r][d];
        nrm = fmaf(qd, kss[d], nrm);
        const float4 k0 = *(const float4*)&KVs[d][e0 + 0];
        const float4 k1 = *(const float4*)&KVs[d][e0 + 4];
        const float4 k2 = *(const float4*)&KVs[d][e0 + 8];
        const float4 k3 = *(const float4*)&KVs[d][e0 + 12];
        out[0]  = fmaf(qd, k0.x, out[0]);  out[1]  = fmaf(qd, k0.y, out[1]);
        out[2]  = fmaf(qd, k0.z, out[2]);  out[3]  = fmaf(qd, k0.w, out[3]);
        out[4]  = fmaf(qd, k1.x, out[4]);  out[5]  = fmaf(qd, k1.y, out[5]);
        out[6]  = fmaf(qd, k1.z, out[6]);  out[7]  = fmaf(qd, k1.w, out[7]);
        out[8]  = fmaf(qd, k2.x, out[8]);  out[9]  = fmaf(qd, k2.y, out[9]);
        out[10] = fmaf(qd, k2.z, out[10]); out[11] = fmaf(qd, k2.w, out[11]);
        out[12] = fmaf(qd, k3.x, out[12]); out[13] = fmaf(qd, k3.y, out[13]);
        out[14] = fmaf(qd, k3.z, out[14]); out[15] = fmaf(qd, k3.w, out[15]);
    }

    const float inv = 1.f / (nrm + 1e-6f);
    const size_t gb = ((size_t)b * SEQ + s0 + r) * 2048 + h * HDIM + e0;
#pragma unroll
    for (int g4 = 0; g4 < 4; ++g4) {
        ushort4 H, L;
        const float v0 = out[g4*4+0] * inv;
        const float v1 = out[g4*4+1] * inv;
        const float v2 = out[g4*4+2] * inv;
        const float v3 = out[g4*4+3] * inv;
        H.x = f2bf(v0); L.x = f2bf(v0 - bf2f(H.x));
        H.y = f2bf(v1); L.y = f2bf(v1 - bf2f(H.y));
        H.z = f2bf(v2); L.z = f2bf(v2 - bf2f(H.z));
        H.w = f2bf(v3); L.w = f2bf(v3 - bf2f(H.w));
        *(ushort4*)&att[gb + g4 * 4]        = H;
        *(ushort4*)&att[gb + 1024 + g4 * 4] = L;
    }
}

// ---------------------------------------------------------------------------
extern "C" void kernel_launch(void* const* d_in, const int* in_sizes, int n_in,
                              void* d_out, int out_size, void* d_ws, size_t ws_size,
                              hipStream_t stream)
{
    const float* x  = (const float*)d_in[0];
    const float* Wq = (const float*)d_in[1];
    const float* bq = (const float*)d_in[2];
    const float* Wk = (const float*)d_in[3];
    const float* bk = (const float*)d_in[4];
    const float* Wv = (const float*)d_in[5];
    const float* bv = (const float*)d_in[6];
    const float* Wo = (const float*)d_in[7];
    const float* bo = (const float*)d_in[8];

    // workspace layout (~153 MB):
    unsigned short* xs  = (unsigned short*)d_ws;                   // [16384][2048] = [xh|xl], later att
    unsigned short* wsp = xs + (size_t)NROWS * 2048;               // 4 x [1024][2048] = [Wh|Wl] per matrix
    float* buf0 = (float*)(wsp + 4u * W1);                         // k, then q (fp32)
    float* kv   = buf0 + (size_t)NROWS * DMODEL;                   // [NBH][64][64]
    float* ksum = kv + NBH * HDIM * HDIM;                          // [NBH][64]
    float* kvp  = ksum + NBH * HDIM;                               // [SCHUNK][NBH][64][64]
    float* ksp  = kvp + (size_t)SCHUNK * NBH * HDIM * HDIM;        // [SCHUNK][NBH][64]
    float* vbuf = (float*)d_out;                                   // v lives in d_out (dead before final GEMM)

    const dim3 gg(256);   // (16384/256) x (1024/256) = 64 x 4, flat + XCD swizzle

    // convert weights + x to bf16 hi/lo concat layouts
    split_w4<<<dim3(1024, 4), 256, 0, stream>>>(Wq, Wk, Wv, Wo, wsp);
    split_x<<<16384, 256, 0, stream>>>(x, xs);
    // k = elu(x@Wk^T + bk)+1 ; v = x@Wv^T + bv
    gemm_p3<1><<<gg, 512, 0, stream>>>(xs, wsp + 1u * W1, bk, buf0);
    gemm_p3<0><<<gg, 512, 0, stream>>>(xs, wsp + 2u * W1, bv, vbuf);
    // kv, ksum (deterministic split-K + reduce)
    kv_partial<<<dim3(NBH, SCHUNK), 512, 0, stream>>>(buf0, vbuf, kvp, ksp);
    kv_reduce<<<1024, 256, 0, stream>>>(kvp, ksp, kv, ksum);
    // q = elu(x@Wq^T + bq)+1   (overwrites k)
    gemm_p3<1><<<gg, 512, 0, stream>>>(xs, wsp, bq, buf0);
    // att = (q@kv)/(q@ksum + 1e-6), fused hi/lo split into xs (x is dead)
    qkv_norm<<<dim3(SEQ / 64, NBATCH, NHEAD), 256, 0, stream>>>(buf0, kv, ksum, xs);
    // out = att@Wo^T + bo  (overwrites v in d_out)
    gemm_p3<0><<<gg, 512, 0, stream>>>(xs, wsp + 3u * W1, bo, (float*)d_out);
}